// Round 7
// baseline (185.624 us; speedup 1.0000x reference)
//
#include <hip/hip_runtime.h>
#include <math.h>

// EdgeDetection: fused gray -> gauss3x3(sigma=0.8) -> scharr -> L2 mag, reflect-101
// Composite separable 5-tap: sx = (vert [3,10,3]*g) x (horiz [-1,0,1]*g), sy = transpose.
// R9: PIPELINED persistent strips (T3/T4-lite). R6 counters: async staging worked
// (VGPR 52, no conflicts) but issue->drain(0)->compute still convoys chip-wide at
// 2.9 TB/s vs 6.8 TB/s demonstrated (fillBuffer). Now: each block = 128x128 strip
// = 8 tiles of 16 rows; double-buffered LDS (2x36.9KB -> 2 blocks/CU, grid 512 =
// exact residency); stage tile t+1 while computing tile t; COUNTED s_waitcnt vmcnt
// (15 steady / 9 head / 6 tail; never 0 mid-loop) so next tile's loads stay in
// flight across compute; raw s_barrier (no auto vmcnt(0) drain) + sched_barrier(0).

#define IMG_H 1024
#define IMG_W 1024
#define TW 128
#define TH 16
#define NT 8                 // tiles per strip (strip = 128 rows)
#define GCOLS 136            // staged cols x0-4 .. x0+131 (34 float4 per row)
#define ITEMS 768            // float4 slots per channel: 680 real (20 rows x 34) + 88 pad

// 1D gaussian sigma=0.8 k=3: e=exp(-0.78125); W0=1/(1+2e), W1=e/(1+2e)
#define W0 0.52201125f
#define W1 0.23899437f
// composite smooth taps conv([3,10,3],[W1,W0,W1]):
#define AV0 0.71698311f   // 3*W1
#define AV1 3.95597745f   // 3*W0 + 10*W1
#define AV2 6.65407872f   // 10*W0 + 6*W1

typedef float vf4 __attribute__((ext_vector_type(4)));
#define AS_GLOBAL const __attribute__((address_space(1))) void*
#define AS_LDS __attribute__((address_space(3))) void*

__device__ __forceinline__ int reflect101(int v, int n) {
    v = (v < 0) ? -v : v;
    return (v >= n) ? (2 * n - 2 - v) : v;
}

__global__ __launch_bounds__(256, 2)
void edge_kernel(const float* __restrict__ in, float* __restrict__ out) {
    // [2 buffers][3 channels][768 float4 slots] = 73728 B -> 2 blocks/CU
    __shared__ __align__(16) float sAll[2][3][ITEMS * 4];

    const int tid = threadIdx.x;
    const int bx = blockIdx.x, sy = blockIdx.y, b = blockIdx.z;
    const int x0 = bx * TW;
    const int ybase = sy * (TH * NT);

    const size_t plane = (size_t)IMG_H * IMG_W;
    const float* pr = in + (size_t)b * 3 * plane;
    const float* pg = pr + plane;
    const float* pb = pg + plane;
    float* po = out + (size_t)b * 3 * plane;

    // 9 async loads/thread per tile (3 slots x 3 channels), guard-free, item-linear
    // LDS dest (wave-uniform base + lane*16 pattern required by global_load_lds).
    auto STAGE = [&](int bufi, int ty0) {
        #pragma unroll
        for (int k = 0; k < 3; ++k) {
            const int item = tid + k * 256;
            const int gy = item / 34;             // rows 0..19 real, 20..22 junk pad
            const int g4 = (item - gy * 34) * 4;
            const int y = reflect101(ty0 - 2 + gy, IMG_H);
            int x = x0 - 4 + g4;
            x = x < 0 ? 0 : (x > IMG_W - 4 ? IMG_W - 4 : x);  // clamp; edge fixed in regs
            const size_t o = (size_t)y * IMG_W + x;
            __builtin_amdgcn_global_load_lds((AS_GLOBAL)(pr + o), (AS_LDS)&sAll[bufi][0][item * 4], 16, 0, 0);
            __builtin_amdgcn_global_load_lds((AS_GLOBAL)(pg + o), (AS_LDS)&sAll[bufi][1][item * 4], 16, 0, 0);
            __builtin_amdgcn_global_load_lds((AS_GLOBAL)(pb + o), (AS_LDS)&sAll[bufi][2][item * 4], 16, 0, 0);
        }
    };

    const int tx = tid & 31;        // col group: cols c4..c4+3
    const int tyg = tid >> 5;       // 0..7
    const int c4 = tx * 4;
    const int r0 = tyg * 2;         // output rows (within tile) r0, r0+1
    const bool eBL = (bx == 0) && (tx == 0);
    const bool eBR = (bx == (IMG_W / TW - 1)) && (tx == 31);

    STAGE(0, ybase);                // prologue: tile 0 in flight

    #pragma unroll
    for (int t = 0; t < NT; ++t) {
        const int cur = t & 1;
        if (t < NT - 1) STAGE(cur ^ 1, ybase + (t + 1) * TH);   // tile t+1 in flight

        // Retire exactly tile t's 9 loads. Per-wave VMEM FIFO:
        //   t==0:        [t0 loads(9)][t1 loads(9)]            -> wait <=9
        //   0<t<NT-1:    [t loads(9)][prev stores(6)][t+1 (9)] -> wait <=15
        //   t==NT-1:     [t loads(9)][prev stores(6)]          -> wait <=6
        if (t == 0)            asm volatile("s_waitcnt vmcnt(9)"  ::: "memory");
        else if (t == NT - 1)  asm volatile("s_waitcnt vmcnt(6)"  ::: "memory");
        else                   asm volatile("s_waitcnt vmcnt(15)" ::: "memory");

        // ---- convert own slots to gray, in place in channel 0 (race-free) ----
        #pragma unroll
        for (int k = 0; k < 3; ++k) {
            const int i4 = (tid + k * 256) * 4;
            float4 r  = *(const float4*)&sAll[cur][0][i4];
            float4 g  = *(const float4*)&sAll[cur][1][i4];
            float4 bb = *(const float4*)&sAll[cur][2][i4];
            float4 gr;
            gr.x = 0.299f * r.x + 0.587f * g.x + 0.114f * bb.x;
            gr.y = 0.299f * r.y + 0.587f * g.y + 0.114f * bb.y;
            gr.z = 0.299f * r.z + 0.587f * g.z + 0.114f * bb.z;
            gr.w = 0.299f * r.w + 0.587f * g.w + 0.114f * bb.w;
            *(float4*)&sAll[cur][0][i4] = gr;
        }
        asm volatile("s_waitcnt lgkmcnt(0)" ::: "memory");  // convert writes visible
        __builtin_amdgcn_s_barrier();
        __builtin_amdgcn_sched_barrier(0);

        // ---- compute 2 output rows from 6 hrows of gray ----
        const int ty0 = ybase + t * TH;
        float hs[6][4], hd[6][4];
        #pragma unroll
        for (int s = 0; s < 6; ++s) {
            const float* row = &sAll[cur][0][(r0 + s) * GCOLS + c4];
            float4 ga = *(const float4*)(row);
            float4 gb = *(const float4*)(row + 4);
            float4 gc = *(const float4*)(row + 8);
            float g[12] = {ga.x, ga.y, ga.z, ga.w, gb.x, gb.y, gb.z, gb.w,
                           gc.x, gc.y, gc.z, gc.w};
            if (eBL) { g[2] = g[6]; g[3] = g[5]; }   // reflect-101 x-edge fixup
            if (eBR) { g[8] = g[6]; g[9] = g[5]; }
            #pragma unroll
            for (int k = 0; k < 4; ++k) {
                hs[s][k] = AV0 * (g[k+2] + g[k+6]) + AV1 * (g[k+3] + g[k+5]) + AV2 * g[k+4];
                hd[s][k] = W1 * (g[k+6] - g[k+2]) + W0 * (g[k+5] - g[k+3]);
            }
        }

        #pragma unroll
        for (int t2 = 0; t2 < 2; ++t2) {
            vf4 mag;
            #pragma unroll
            for (int k = 0; k < 4; ++k) {
                float sx = AV0 * (hd[t2][k] + hd[t2+4][k]) + AV1 * (hd[t2+1][k] + hd[t2+3][k]) + AV2 * hd[t2+2][k];
                float sy2 = W1 * (hs[t2+4][k] - hs[t2][k]) + W0 * (hs[t2+3][k] - hs[t2+1][k]);
                mag[k] = sqrtf(sx * sx + sy2 * sy2);
            }
            const size_t o = (size_t)(ty0 + r0 + t2) * IMG_W + (x0 + c4);
            __builtin_nontemporal_store(mag, (vf4*)(po + o));
            __builtin_nontemporal_store(mag, (vf4*)(po + o + plane));
            __builtin_nontemporal_store(mag, (vf4*)(po + o + 2 * plane));
        }

        // all waves done reading buf[cur] before next iter's STAGE overwrites it
        __builtin_amdgcn_s_barrier();
        __builtin_amdgcn_sched_barrier(0);
    }
}

extern "C" void kernel_launch(void* const* d_in, const int* in_sizes, int n_in,
                              void* d_out, int out_size, void* d_ws, size_t ws_size,
                              hipStream_t stream) {
    const float* in = (const float*)d_in[0];
    float* out = (float*)d_out;
    const int B = in_sizes[0] / (3 * IMG_H * IMG_W);
    dim3 grid(IMG_W / TW, IMG_H / (TH * NT), B);   // 8 x 8 x B = 512 blocks
    edge_kernel<<<grid, dim3(256), 0, stream>>>(in, out);
}